// Round 14
// baseline (292.587 us; speedup 1.0000x reference)
//
#include <hip/hip_runtime.h>
#include <math.h>

typedef __attribute__((ext_vector_type(8))) __bf16 bf16x8;
typedef __attribute__((ext_vector_type(4))) __bf16 bf16x4;
typedef __attribute__((ext_vector_type(4))) float f32x4;

#define DEV static __device__ __forceinline__

DEV float b2f(unsigned short u){ union{unsigned i; float f;} c; c.i=((unsigned)u)<<16; return c.f; }
DEV unsigned short f2b(float f){
  union{float f; unsigned u;} c; c.f=f;
  unsigned r = 0x7FFFu + ((c.u>>16)&1u);
  return (unsigned short)((c.u + r)>>16);
}
DEV unsigned pack2(float a, float b){ return (unsigned)f2b(a) | ((unsigned)f2b(b)<<16); }
DEV float gelu_exact(float x){ return 0.5f*x*(1.f+erff(x*0.70710678118654752f)); }

typedef __attribute__((address_space(1))) void gas_void;
typedef __attribute__((address_space(3))) void las_void;
DEV void gload_lds16(const unsigned short* g, unsigned short* l){
  __builtin_amdgcn_global_load_lds((const gas_void*)g, (las_void*)l, 16, 0, 0);
}

template<int N> DEV void waitcnt_vm(){
  if constexpr(N==0)      asm volatile("s_waitcnt vmcnt(0)" ::: "memory");
  else if constexpr(N==2) asm volatile("s_waitcnt vmcnt(2)" ::: "memory");
  else if constexpr(N==3) asm volatile("s_waitcnt vmcnt(3)" ::: "memory");
  else if constexpr(N==4) asm volatile("s_waitcnt vmcnt(4)" ::: "memory");
  else if constexpr(N==6) asm volatile("s_waitcnt vmcnt(6)" ::: "memory");
  else if constexpr(N==8) asm volatile("s_waitcnt vmcnt(8)" ::: "memory");
  else                    asm volatile("s_waitcnt vmcnt(0)" ::: "memory");
}

// ---------------- mega prep: casts + 4 weight transposes in ONE dispatch -------
// block id ranges: [0,4096) cast x; [4096,12288) cast firing;
// [12288,14336) trT w_router (64x32); [14336,18432) trT w_pool (32x128);
// [18432,21504) trT w_in (96x32); [21504,22528) trT w_ao (32x32).
DEV void dev_cast(const float* in, unsigned short* out, long i){
  float4 v = ((const float4*)in)[i];
  ushort4 o; o.x=f2b(v.x); o.y=f2b(v.y); o.z=f2b(v.z); o.w=f2b(v.w);
  ((ushort4*)out)[i] = o;
}
__global__ __launch_bounds__(256) void k_prep(
    const float* __restrict__ x,        unsigned short* __restrict__ xb,
    const float* __restrict__ firing,   unsigned short* __restrict__ firb,
    const float* __restrict__ w_router, unsigned short* __restrict__ wrT,
    const float* __restrict__ w_pool,   unsigned short* __restrict__ wpoT,
    const float* __restrict__ w_in,     unsigned short* __restrict__ winT,
    const float* __restrict__ w_ao,     unsigned short* __restrict__ waoT)
{
  __shared__ float tile[32][33];
  const int id = blockIdx.x, tid = threadIdx.x;
  if (id < 4096) { dev_cast(x, xb, (long)id*256 + tid); return; }
  if (id < 12288) { dev_cast(firing, firb, (long)(id-4096)*256 + tid); return; }
  const float* in; unsigned short* out; int R, C, bx, by;
  if (id < 14336) { int i2=id-12288; in=w_router; out=wrT; R=1024; C=2048; bx=i2&63;  by=i2>>6; }
  else if (id < 18432) { int i2=id-14336; in=w_pool; out=wpoT; R=4096; C=1024; bx=i2&31; by=i2>>5; }
  else if (id < 21504) { int i2=id-18432; in=w_in;  out=winT; R=1024; C=3072; bx=i2%96; by=i2/96; }
  else { int i2=id-21504; in=w_ao; out=waoT; R=1024; C=1024; bx=i2&31; by=i2>>5; }
  const int tc = bx*32, tr = by*32;
  {
    const int r = tid>>3, c4 = (tid&7)*4;
    float4 v = *(const float4*)&in[(long)(tr+r)*C + tc+c4];
    tile[r][c4+0]=v.x; tile[r][c4+1]=v.y; tile[r][c4+2]=v.z; tile[r][c4+3]=v.w;
  }
  __syncthreads();
  {
    const int c = tid>>3, r4 = (tid&7)*4;
    ushort4 o;
    o.x = f2b(tile[r4+0][c]); o.y = f2b(tile[r4+1][c]);
    o.z = f2b(tile[r4+2][c]); o.w = f2b(tile[r4+3][c]);
    *(ushort4*)&out[(long)(tc+c)*R + tr+r4] = o;
  }
}

// -- 3-buffer counted-vmcnt bf16 MFMA GEMM, wave-grid WRxWC, per-wave FMxFN ----
template<int WR, int WC, int FM, int FN, int OMODE>
__global__ __launch_bounds__(WR*WC*64, 2) void k_gemm_bt(
  const unsigned short* __restrict__ A, long lda, long sAb,
  const unsigned short* __restrict__ Bt, long ldb, long sBb,
  float* __restrict__ Cf, unsigned short* __restrict__ Cb, long ldc, long sCb,
  const float* __restrict__ bias, int Kiters)
{
  constexpr int WAVES = WR*WC;
  constexpr int BM = WR*FM*16, BN = WC*FN*16;
  constexpr int AR16 = BM/16, TOT16 = (BM+BN)/16;   // 16-row stage units
  constexpr int UNITS = TOT16/WAVES;                // gload_lds per wave per tile
  static_assert(TOT16 % WAVES == 0, "stage units must split across waves");
  __shared__ __align__(16) unsigned short S[3][TOT16*512];
  const int tid = threadIdx.x;
  const int wave = tid>>6, lane = tid&63;
  const int wr = wave/WC, wc = wave%WC;
  const int l15 = lane&15, lhi = lane>>4;
  const int lrow = lane>>2;
  const int lcol = ((lane&3) ^ ((lrow>>1)&3))*8;    // 2-way swizzled source slot

  // XCD-aware bijective swizzle within the z-slice (requires nwg % 8 == 0)
  const int gx = gridDim.x;
  const int nwg = gx*gridDim.y;
  const int id = blockIdx.y*gx + blockIdx.x;
  const int sid = (id&7)*(nwg>>3) + (id>>3);
  const long bm = (long)(sid / gx)*BM, bn = (long)(sid % gx)*BN;

  const unsigned short* Ab  = A  + (long)blockIdx.z*sAb + bm*lda;
  const unsigned short* Btb = Bt + (long)blockIdx.z*sBb + bn*ldb;

  f32x4 acc[FM][FN];
  #pragma unroll
  for (int i=0;i<FM;i++)
    #pragma unroll
    for (int j=0;j<FN;j++) acc[i][j] = (f32x4){0.f,0.f,0.f,0.f};

  auto STAGE = [&](int kt, int buf){
    const long k0 = (long)kt*32;
    #pragma unroll
    for (int u=0; u<UNITS; ++u) {
      const int t = wave + u*WAVES;                  // wave-uniform stage unit
      const unsigned short* g;
      if (t < AR16) g = Ab  + (long)(t*16 + lrow)*lda + k0 + lcol;
      else          g = Btb + (long)((t-AR16)*16 + lrow)*ldb + k0 + lcol;
      gload_lds16(g, &S[buf][t*512]);                // linear dest, swz source
    }
  };
  auto COMPUTE = [&](int buf){
    const unsigned short* Sb = S[buf];
    bf16x8 bfr[FN];
    #pragma unroll
    for (int j=0;j<FN;j++) {
      const int r = wc*(FN*16) + j*16 + l15;
      bfr[j] = *(const bf16x8*)&Sb[BM*32 + r*32 + ((lhi ^ ((r>>1)&3))*8)];
    }
    #pragma unroll
    for (int i=0;i<FM;i++) {
      const int r = wr*(FM*16) + i*16 + l15;
      bf16x8 a = *(const bf16x8*)&Sb[r*32 + ((lhi ^ ((r>>1)&3))*8)];
      #pragma unroll
      for (int j=0;j<FN;j++)
        acc[i][j] = __builtin_amdgcn_mfma_f32_16x16x32_bf16(a, bfr[j], acc[i][j], 0,0,0);
    }
  };

  STAGE(0, 0);
  if (Kiters > 1) STAGE(1, 1);
  for (int kt=0; kt<Kiters; ++kt) {
    if (kt+1 < Kiters) waitcnt_vm<UNITS>();          // tile kt retired; kt+1 in flight
    else               waitcnt_vm<0>();              // last tile: full drain
    __builtin_amdgcn_s_barrier();                    // raw barrier: no auto-drain
    __builtin_amdgcn_sched_barrier(0);
    COMPUTE(kt%3);
    if (kt+2 < Kiters) STAGE(kt+2, (kt+2)%3);        // buf freed by barrier above
  }

  #pragma unroll
  for (int i=0;i<FM;i++) {
    #pragma unroll
    for (int j=0;j<FN;j++) {
      long col = bn + wc*(FN*16) + j*16 + l15;
      float bb = bias ? bias[col] : 0.f;
      #pragma unroll
      for (int q=0;q<4;q++) {
        long row = bm + wr*(FM*16) + i*16 + lhi*4 + q;
        float v = acc[i][j][q] + bb;
        long off = (long)blockIdx.z*sCb + row*ldc + col;
        if constexpr (OMODE==0 || OMODE==2) Cf[off] = v;
        if constexpr (OMODE==1 || OMODE==2) Cb[off] = f2b(v);
      }
    }
  }
}

// ---- combine bf16 split-K partials + f32 bias -> bf16 (row = 1024) ----
__global__ __launch_bounds__(256) void k_combine_bias_bf16(
    const unsigned short* __restrict__ p, long sz, const float* __restrict__ bias,
    unsigned short* __restrict__ outb)
{
  const long t = blockIdx.x;
  const int tid = threadIdx.x;
  ushort4 a = ((const ushort4*)(p + t*1024))[tid];
  ushort4 b = ((const ushort4*)(p + sz + t*1024))[tid];
  float4 bi = ((const float4*)bias)[tid];
  ushort4 o;
  o.x = f2b(b2f(a.x)+b2f(b.x)+bi.x); o.y = f2b(b2f(a.y)+b2f(b.y)+bi.y);
  o.z = f2b(b2f(a.z)+b2f(b.z)+bi.z); o.w = f2b(b2f(a.w)+b2f(b.w)+bi.w);
  ((ushort4*)(outb + t*1024))[tid] = o;
}

// ------------- top-16 + softmax over bf16 scores, packed sortable keys --------
__global__ __launch_bounds__(256) void k_topk_softmax(const unsigned short* __restrict__ scores,
                                                      int* __restrict__ topidx,
                                                      float* __restrict__ topw)
{
  const int tid = threadIdx.x, wave = tid>>6, lane = tid&63;
  const long t = blockIdx.x;
  const unsigned short* row = scores + t*2048;
  const int base = wave*512 + lane*8;
  unsigned k0,k1,k2,k3,k4,k5,k6,k7;
  {
    uint4 v4 = *(const uint4*)(row + base);
    unsigned short u[8] = {
      (unsigned short)(v4.x&0xFFFF),(unsigned short)(v4.x>>16),
      (unsigned short)(v4.y&0xFFFF),(unsigned short)(v4.y>>16),
      (unsigned short)(v4.z&0xFFFF),(unsigned short)(v4.z>>16),
      (unsigned short)(v4.w&0xFFFF),(unsigned short)(v4.w>>16) };
    unsigned kk[8];
    #pragma unroll
    for (int e=0;e<8;e++){
      unsigned m = (u[e]&0x8000u) ? (unsigned)(~u[e] & 0xFFFFu)
                                  : ((unsigned)u[e] | 0x8000u);
      kk[e] = (m<<16) | (unsigned)(2047 - (base+e));
    }
    k0=kk[0];k1=kk[1];k2=kk[2];k3=kk[3];k4=kk[4];k5=kk[5];k6=kk[6];k7=kk[7];
  }
  #define CX(x,y) { unsigned mx = x>y?x:y, mn = x>y?y:x; x=mx; y=mn; }
  CX(k0,k1) CX(k2,k3) CX(k4,k5) CX(k6,k7)
  CX(k0,k2) CX(k1,k3) CX(k4,k6) CX(k5,k7)
  CX(k1,k2) CX(k5,k6)
  CX(k0,k4) CX(k1,k5) CX(k2,k6) CX(k3,k7)
  CX(k2,k4) CX(k3,k5)
  CX(k1,k2) CX(k3,k4) CX(k5,k6)
  #undef CX

  __shared__ unsigned wk[4][16];
  unsigned my1 = 0;
  for (int it=0; it<16; ++it){
    unsigned best = k0;
    #pragma unroll
    for (int off=1; off<64; off<<=1){
      unsigned o = __shfl_xor(best, off);
      best = o>best ? o : best;
    }
    if (lane==it) my1 = best;
    bool own = (k0==best);
    k0 = own?k1:k0; k1 = own?k2:k1; k2 = own?k3:k2; k3 = own?k4:k3;
    k4 = own?k5:k4; k5 = own?k6:k5; k6 = own?k7:k6; k7 = own?0u:k7;
  }
  if (lane < 16) wk[wave][lane] = my1;
  __syncthreads();
  if (wave == 0){
    unsigned c = wk[lane>>4][lane&15];
    unsigned my2 = 0;
    for (int it=0; it<16; ++it){
      unsigned best = c;
      #pragma unroll
      for (int off=1; off<64; off<<=1){
        unsigned o = __shfl_xor(best, off);
        best = o>best ? o : best;
      }
      if (lane==it) my2 = best;
      c = (c==best) ? 0u : c;
    }
    int idx = 2047 - (int)(my2 & 0x7FFu);
    float val = -1e30f;
    if (lane < 16) val = b2f(row[idx]);
    float m0 = __shfl(val, 0);                 // lane 0 = first extracted = max
    float e = (lane < 16) ? __expf(val - m0) : 0.f;
    float s = e;
    #pragma unroll
    for (int off=1; off<64; off<<=1) s += __shfl_xor(s, off);
    if (lane < 16){
      topw[t*16+lane]   = e/s;
      topidx[t*16+lane] = idx;
    }
  }
}

// ---- gather + weighted combine + GELU, XCD-partitioned along d_ff ----
__global__ __launch_bounds__(256) void k_gather_gelu(const int* __restrict__ topidx,
                                                     const float* __restrict__ topw,
                                                     const unsigned short* __restrict__ firing,
                                                     unsigned short* __restrict__ gact)
{
  __shared__ int idx[4][16]; __shared__ float w[4][16];
  const int tid = threadIdx.x;
  const int c = blockIdx.x & 7;
  const long t0 = (long)(blockIdx.x >> 3) * 4;
  if (tid < 64) {
    int tok = tid >> 4, k = tid & 15;
    idx[tok][k] = topidx[(t0+tok)*16 + k];
    w[tok][k]   = topw[(t0+tok)*16 + k];
  }
  __syncthreads();
  const int tok = tid >> 6, lane = tid & 63;
  const int f0 = c*512 + lane*8;
  float acc[8] = {0,0,0,0,0,0,0,0};
  #pragma unroll
  for (int k=0;k<16;k++) {
    uint4 v = *(const uint4*)(firing + (long)idx[tok][k]*4096 + f0);
    const unsigned short* pu = (const unsigned short*)&v;
    float wk = w[tok][k];
    #pragma unroll
    for (int e=0;e<8;e++) acc[e] += wk * b2f(pu[e]);
  }
  float g[8];
  #pragma unroll
  for (int e=0;e<8;e++) g[e] = gelu_exact(acc[e]);
  uint4 ov;
  ov.x = pack2(g[0],g[1]); ov.y = pack2(g[2],g[3]);
  ov.z = pack2(g[4],g[5]); ov.w = pack2(g[6],g[7]);
  *(uint4*)(gact + (t0+tok)*4096 + f0) = ov;
}

// ---------------- V transpose per (b,h): vT[bh][d][t] = qkv[b,t][2048+h*64+d] --
__global__ __launch_bounds__(256) void k_vtrans(const unsigned short* __restrict__ qkv,
                                                unsigned short* __restrict__ vT)
{
  __shared__ unsigned short tile[64][65];
  int bh = blockIdx.y; int b = bh>>4, h = bh&15;
  long t0 = (long)blockIdx.x*64;
  const int tid = threadIdx.x;
  #pragma unroll
  for (int s=0;s<16;s++) {
    int i = tid + s*256;
    int r = i>>6, c = i&63;
    tile[r][c] = qkv[ (long)(b*1024 + t0 + r)*3072 + 2048 + h*64 + c ];
  }
  __syncthreads();
  #pragma unroll
  for (int s=0;s<16;s++) {
    int i = tid + s*256;
    int c = i>>6, r = i&63;
    vT[ (long)bh*65536 + (long)c*1024 + t0 + r ] = tile[r][c];
  }
}

// ---------------- fused flash attention v3: K from L2, V in LDS ----------------
// grid = (64 bh, 8 q-tiles), block = 512 (8 waves, 16 q-rows each). K/V are
// XCD-local L2-resident (2MB/XCD, round-11 FETCH 12MB); K fragments read
// DIRECTLY from global (each wave needed the whole K-tile from LDS -> 8x LDS
// amplification; L2 serves the same bytes with no LDS instruction cost).
// Only V stays staged (LDS 32KB, double-buffered).
__global__ __launch_bounds__(512, 4) void k_flash_attn(
  const unsigned short* __restrict__ qkv,   // [4][1024][3072]
  const unsigned short* __restrict__ vT,    // [64 bh][64 d][1024 t]
  unsigned short* __restrict__ ctx)         // [4][1024][1024]
{
  __shared__ __align__(16) unsigned short Vs[2][64*128];
  const int tid = threadIdx.x;
  const int wave = tid>>6, lane = tid&63;
  const int l15 = lane&15, lhi = lane>>4;
  const int bh = blockIdx.x, b = bh>>4, h = bh&15;
  const long q0 = (long)blockIdx.y*128;
  const unsigned short* Qg = qkv + ((long)b*1024 + q0)*3072 + h*64;
  const unsigned short* Kg = qkv + (long)b*1024*3072 + 1024 + h*64;
  const unsigned short* Vg = vT + (long)bh*65536;

  auto STAGE_V = [&](int t, int s){
    const long kv0 = (long)t*128;
    const int vc = (lane&15) ^ ((wave&1)*4 + lhi);   // row r&7 = (wave&1)*4+lhi
    #pragma unroll
    for (int uu=0; uu<2; ++uu){
      int u = wave + uu*8;
      gload_lds16(Vg + (long)(u*4+lhi)*1024 + kv0 + vc*8, &Vs[s][u*512]);
    }
  };

  STAGE_V(0, 0);

  bf16x8 qf[2];
  {
    const long r = wave*16 + l15;
    qf[0] = *(const bf16x8*)(Qg + r*3072 + lhi*8);
    qf[1] = *(const bf16x8*)(Qg + r*3072 + 32 + lhi*8);
  }
  __syncthreads();   // V tile 0 resident

  f32x4 acco[4];
  #pragma unroll
  for (int nf=0;nf<4;nf++) acco[nf] = (f32x4){0.f,0.f,0.f,0.f};
  float m_run = -1e30f, l_run = 0.f;

  int sel = 0;
  for (int t=0; t<8; ++t) {
    if (t < 7) STAGE_V(t+1, sel^1);
    // S^T = K-tile @ Q^T: K fragments straight from L2 (rows fk*16+l15,
    // 4 lanes/row read 64B contiguous -> decent segments)
    const unsigned short* Kt = Kg + (long)t*128*3072;
    f32x4 accs[8];
    #pragma unroll
    for (int fk=0;fk<8;fk++){
      accs[fk] = (f32x4){0.f,0.f,0.f,0.f};
      const unsigned short* kr = Kt + (long)(fk*16 + l15)*3072;
      bf16x8 k0 = *(const bf16x8*)(kr + lhi*8);
      accs[fk] = __builtin_amdgcn_mfma_f32_16x16x32_bf16(k0, qf[0], accs[fk],0,0,0);
      bf16x8 k1 = *(const bf16x8*)(kr + 32 + lhi*8);
      accs[fk] = __builtin_amdgcn_mfma_f32_16x16x32_bf16(k1, qf[1], accs[fk],0,0,0);
    }
    float mt = -1e30f;
    #pragma unroll
    for (int fk=0;fk<8;fk++)
      #pragma unroll
      for (int q=0;q<4;q++) mt = fmaxf(mt, accs[fk][q]);
    mt = fmaxf(mt, __shfl_xor(mt,16));
    mt = fmaxf(mt, __shfl_xor(mt,32));
    mt *= 0.125f;
    if (!__all(mt <= m_run + 8.f)) {                  // T13 defer-max, THR=8
      float mnew = fmaxf(m_run, mt);
      float fj = __expf(m_run - mnew);
      l_run *= fj;
      #pragma unroll
      for (int q=0;q<4;q++){
        float fr = __shfl(fj, (lane&48)|(lhi*4+q));   // O-row q' = lhi*4+q
        #pragma unroll
        for (int nf=0;nf<4;nf++) acco[nf][q] *= fr;
      }
      m_run = mnew;
    }
    bf16x8 pa[4];
    float ssum = 0.f;
    #pragma unroll
    for (int fk=0;fk<8;fk++)
      #pragma unroll
      for (int q=0;q<4;q++){
        float p = __expf(accs[fk][q]*0.125f - m_run);
        ssum += p;
        pa[fk>>1][(fk&1)*4+q] = (__bf16)p;            // k = (fk>>1)*32+(fk&1)*16+lhi*4+q
      }
    ssum += __shfl_xor(ssum,16);
    ssum += __shfl_xor(ssum,32);
    l_run += ssum;
    #pragma unroll
    for (int kk=0;kk<4;kk++)
      #pragma unroll
      for (int nf=0;nf<4;nf++){
        const int rv = nf*16 + l15;
        const int cb = kk*4 + (lhi>>1);
        bf16x4 v0 = *(const bf16x4*)&Vs[sel][rv*128 + (( cb   ^(l15&7))*8) + (lhi&1)*4];
        bf16x4 v1 = *(const bf16x4*)&Vs[sel][rv*128 + (((cb+2)^(l15&7))*8) + (lhi&1)*4];
        bf16x8 vb = __builtin_shufflevector(v0, v1, 0,1,2,3,4,5,6,7);
        acco[nf] = __builtin_amdgcn_mfma_f32_16x16x32_bf16(pa[kk], vb, acco[nf],0,0,0);
      }
    __syncthreads();    // V tile t+1 resident; buffer safe to swap
    sel ^= 1;
  }

  #pragma unroll
  for (int q=0;q<4;q++){
    float lr = __shfl(l_run, (lane&48)|(lhi*4+q));
    float inv = 1.f/lr;
    long row = q0 + wave*16 + lhi*4 + q;
    #pragma unroll
    for (int nf=0;nf<4;nf++)
      ctx[((long)b*1024 + row)*1024 + h*64 + nf*16 + l15] = f2b(acco[nf][q]*inv);
  }
}

// ------- fused double residual+LN: out = LN2( LN1(x + attnb) + neub ) ---------
__global__ __launch_bounds__(256) void k_ln2(const float* __restrict__ x,
                                             const unsigned short* __restrict__ attnb,
                                             const unsigned short* __restrict__ neub,
                                             const float* __restrict__ g1,
                                             const float* __restrict__ be1,
                                             const float* __restrict__ g2,
                                             const float* __restrict__ be2,
                                             float* __restrict__ out)
{
  const long t = blockIdx.x;
  const int tid = threadIdx.x;
  const int wave = tid>>6, lane = tid&63;
  __shared__ float s1[4], s2[4], s3[4], s4[4];
  float4 xv = ((const float4*)(x + t*1024))[tid];
  ushort4 ua = ((const ushort4*)(attnb + t*1024))[tid];
  float4 sv = { xv.x + b2f(ua.x), xv.y + b2f(ua.y),
                xv.z + b2f(ua.z), xv.w + b2f(ua.w) };
  float sum = sv.x+sv.y+sv.z+sv.w;
  float sq  = sv.x*sv.x + sv.y*sv.y + sv.z*sv.z + sv.w*sv.w;
  #pragma unroll
  for (int off=32; off; off>>=1){ sum += __shfl_xor(sum,off); sq += __shfl_xor(sq,off); }
  if (lane==0){ s1[wave]=sum; s2[wave]=sq; }
  __syncthreads();
  sum = s1[0]+s1[1]+s1[2]+s1[3];
  sq  = s2[0]+s2[1]+s2[2]+s2[3];
  float mu  = sum * (1.f/1024.f);
  float var = sq * (1.f/1024.f) - mu*mu;
  float rs  = rsqrtf(var + 1e-5f);
  float4 g1v  = ((const float4*)g1)[tid];
  float4 be1v = ((const float4*)be1)[tid];
  ushort4 un = ((const ushort4*)(neub + t*1024))[tid];
  float4 hv = { (sv.x-mu)*rs*g1v.x + be1v.x + b2f(un.x),
                (sv.y-mu)*rs*g1v.y + be1v.y + b2f(un.y),
                (sv.z-mu)*rs*g1v.z + be1v.z + b2f(un.z),
                (sv.w-mu)*rs*g1v.w + be1v.w + b2f(un.w) };
  float sum2 = hv.x+hv.y+hv.z+hv.w;
  float sq2  = hv.x*hv.x + hv.y*hv.y + hv.z*hv.z + hv.w*hv.w;
  #pragma unroll
  for (int off=32; off; off>>=1){ sum2 += __shfl_xor(sum2,off); sq2 += __shfl_xor(sq2,off); }
  if (lane==0){ s3[wave]=sum2; s4[wave]=sq2; }
  __syncthreads();
  sum2 = s3[0]+s3[1]+s3[2]+s3[3];
  sq2  = s4[0]+s4[1]+s4[2]+s4[3];
  float mu2  = sum2 * (1.f/1024.f);
  float var2 = sq2 * (1.f/1024.f) - mu2*mu2;
  float rs2  = rsqrtf(var2 + 1e-5f);
  float4 g2v  = ((const float4*)g2)[tid];
  float4 be2v = ((const float4*)be2)[tid];
  float4 ov = { (hv.x-mu2)*rs2*g2v.x + be2v.x,
                (hv.y-mu2)*rs2*g2v.y + be2v.y,
                (hv.z-mu2)*rs2*g2v.z + be2v.z,
                (hv.w-mu2)*rs2*g2v.w + be2v.w };
  ((float4*)(out + t*1024))[tid] = ov;
}

// =====================================================================
extern "C" void kernel_launch(void* const* d_in, const int* in_sizes, int n_in,
                              void* d_out, int out_size, void* d_ws, size_t ws_size,
                              hipStream_t stream)
{
  const float* x        = (const float*)d_in[0];
  const float* w_router = (const float*)d_in[1];
  const float* b_router = (const float*)d_in[2];
  const float* firing   = (const float*)d_in[3];
  const float* w_pool   = (const float*)d_in[4];
  const float* b_pool   = (const float*)d_in[5];
  const float* w_in     = (const float*)d_in[6];
  const float* b_in     = (const float*)d_in[7];
  const float* w_ao     = (const float*)d_in[8];
  const float* b_ao     = (const float*)d_in[9];
  const float* g1       = (const float*)d_in[10];
  const float* be1      = (const float*)d_in[11];
  const float* g2       = (const float*)d_in[12];
  const float* be2      = (const float*)d_in[13];
  float* out = (float*)d_out;
  char* ws = (char*)d_ws;

  // ws layout (bytes); P region aliased: scoresb(bf16,16MB) -> gact(bf16,32MB).
  // poolpb (16MB bf16 split-K partials) aliases vT+ctx (written later).
  unsigned short* xb    = (unsigned short*)(ws + 0);          //  8,388,608
  unsigned short* wrT   = (unsigned short*)(ws + 8388608);    //  4,194,304
  unsigned short* firb  = (unsigned short*)(ws + 12582912);   // 16,777,216
  unsigned short* wpoT  = (unsigned short*)(ws + 29360128);   //  8,388,608
  unsigned short* winT  = (unsigned short*)(ws + 37748736);   //  6,291,456
  unsigned short* waoT  = (unsigned short*)(ws + 44040192);   //  2,097,152
  unsigned short* scoresb = (unsigned short*)(ws + 46137344); // 16,777,216 (P)
  unsigned short* gact  = (unsigned short*)(ws + 46137344);   // alias P (32MB)
  int*    topi          = (int*)(ws + 79691776);              //    262,144
  float*  topw          = (float*)(ws + 79953920);            //    262,144
  unsigned short* attnb = (unsigned short*)(ws + 80216064);   //  8,388,608
  unsigned short* neub  = (unsigned short*)(ws + 96993280);   //  8,388,608
  unsigned short* qkvb  = (unsigned short*)(ws + 105381888);  // 25,165,824
  unsigned short* vT    = (unsigned short*)(ws + 130547712);  //  8,388,608
  unsigned short* ctx   = (unsigned short*)(ws + 138936320);  //  8,388,608
  unsigned short* poolpb= (unsigned short*)(ws + 130547712);  // 16,777,216 alias

  if (ws_size < 164102144u) return; // insufficient scratch: fail loudly

  // ---- prep: all casts + weight transposes in one dispatch ----
  k_prep<<<22528, 256, 0, stream>>>(x, xb, firing, firb, w_router, wrT,
                                    w_pool, wpoT, w_in, winT, w_ao, waoT);

  // ---- router: scores = x @ w_router + b_router -> bf16 (128x128, 512 wg) ----
  k_gemm_bt<2,2,4,4,1><<<dim3(16,32,1),256,0,stream>>>(xb,1024,0, wrT,1024,0,
        nullptr,scoresb,2048,0, b_router, 32);
  k_topk_softmax<<<4096,256,0,stream>>>(scoresb, topi, topw);
  k_gather_gelu<<<8192,256,0,stream>>>(topi, topw, firb, gact);

  // ---- pool: split-K=2, 128x128 tiles, bf16 partials; combine adds bias ----
  k_gemm_bt<2,2,4,4,1><<<dim3(8,32,2),256,0,stream>>>(gact,4096,2048, wpoT,4096,2048,
        nullptr,poolpb,1024,4194304, nullptr, 64);
  k_combine_bias_bf16<<<4096,256,0,stream>>>(poolpb, 4194304, b_pool, neub);

  // ---- qkv = neuron_out @ w_in + b_in (bf16; 128x128, 768 wg) ----
  k_gemm_bt<2,2,4,4,1><<<dim3(24,32,1),256,0,stream>>>(neub,1024,0, winT,1024,0,
        nullptr,qkvb,3072,0, b_in, 32);

  // ---- attention: V transpose + fused flash (K from L2, V in LDS) ----
  k_vtrans<<<dim3(16,64),256,0,stream>>>(qkvb, vT);
  k_flash_attn<<<dim3(64,8),512,0,stream>>>(qkvb, vT, ctx);

  // ---- attn_out = ctx @ w_attn_out + b_ao (128x64, 512 wg, bf16 out) ----
  k_gemm_bt<2,2,4,2,1><<<dim3(16,32,1),256,0,stream>>>(ctx,1024,0, waoT,1024,0,
        nullptr,attnb,1024,0, b_ao, 32);

  // ---- out = LN2( LN1(x + attn_out) + neuron_out )  (fused, no hbuf) ----
  k_ln2<<<4096,256,0,stream>>>(x, attnb, neub, g1, be1, g2, be2, out);
}

// Round 15
// 259.842 us; speedup vs baseline: 1.1260x; 1.1260x over previous
//
#include <hip/hip_runtime.h>
#include <math.h>

typedef __attribute__((ext_vector_type(8))) __bf16 bf16x8;
typedef __attribute__((ext_vector_type(4))) __bf16 bf16x4;
typedef __attribute__((ext_vector_type(4))) float f32x4;

#define DEV static __device__ __forceinline__

DEV float b2f(unsigned short u){ union{unsigned i; float f;} c; c.i=((unsigned)u)<<16; return c.f; }
DEV unsigned short f2b(float f){
  union{float f; unsigned u;} c; c.f=f;
  unsigned r = 0x7FFFu + ((c.u>>16)&1u);
  return (unsigned short)((c.u + r)>>16);
}
DEV unsigned pack2(float a, float b){ return (unsigned)f2b(a) | ((unsigned)f2b(b)<<16); }
DEV float gelu_exact(float x){ return 0.5f*x*(1.f+erff(x*0.70710678118654752f)); }

typedef __attribute__((address_space(1))) void gas_void;
typedef __attribute__((address_space(3))) void las_void;
DEV void gload_lds16(const unsigned short* g, unsigned short* l){
  __builtin_amdgcn_global_load_lds((const gas_void*)g, (las_void*)l, 16, 0, 0);
}

template<int N> DEV void waitcnt_vm(){
  if constexpr(N==0)      asm volatile("s_waitcnt vmcnt(0)" ::: "memory");
  else if constexpr(N==2) asm volatile("s_waitcnt vmcnt(2)" ::: "memory");
  else if constexpr(N==3) asm volatile("s_waitcnt vmcnt(3)" ::: "memory");
  else if constexpr(N==4) asm volatile("s_waitcnt vmcnt(4)" ::: "memory");
  else if constexpr(N==6) asm volatile("s_waitcnt vmcnt(6)" ::: "memory");
  else if constexpr(N==8) asm volatile("s_waitcnt vmcnt(8)" ::: "memory");
  else                    asm volatile("s_waitcnt vmcnt(0)" ::: "memory");
}

// ---------------- mega prep: casts + 4 weight transposes in ONE dispatch -------
DEV void dev_cast(const float* in, unsigned short* out, long i){
  float4 v = ((const float4*)in)[i];
  ushort4 o; o.x=f2b(v.x); o.y=f2b(v.y); o.z=f2b(v.z); o.w=f2b(v.w);
  ((ushort4*)out)[i] = o;
}
__global__ __launch_bounds__(256) void k_prep(
    const float* __restrict__ x,        unsigned short* __restrict__ xb,
    const float* __restrict__ firing,   unsigned short* __restrict__ firb,
    const float* __restrict__ w_router, unsigned short* __restrict__ wrT,
    const float* __restrict__ w_pool,   unsigned short* __restrict__ wpoT,
    const float* __restrict__ w_in,     unsigned short* __restrict__ winT,
    const float* __restrict__ w_ao,     unsigned short* __restrict__ waoT)
{
  __shared__ float tile[32][33];
  const int id = blockIdx.x, tid = threadIdx.x;
  if (id < 4096) { dev_cast(x, xb, (long)id*256 + tid); return; }
  if (id < 12288) { dev_cast(firing, firb, (long)(id-4096)*256 + tid); return; }
  const float* in; unsigned short* out; int R, C, bx, by;
  if (id < 14336) { int i2=id-12288; in=w_router; out=wrT; R=1024; C=2048; bx=i2&63;  by=i2>>6; }
  else if (id < 18432) { int i2=id-14336; in=w_pool; out=wpoT; R=4096; C=1024; bx=i2&31; by=i2>>5; }
  else if (id < 21504) { int i2=id-18432; in=w_in;  out=winT; R=1024; C=3072; bx=i2%96; by=i2/96; }
  else { int i2=id-21504; in=w_ao; out=waoT; R=1024; C=1024; bx=i2&31; by=i2>>5; }
  const int tc = bx*32, tr = by*32;
  {
    const int r = tid>>3, c4 = (tid&7)*4;
    float4 v = *(const float4*)&in[(long)(tr+r)*C + tc+c4];
    tile[r][c4+0]=v.x; tile[r][c4+1]=v.y; tile[r][c4+2]=v.z; tile[r][c4+3]=v.w;
  }
  __syncthreads();
  {
    const int c = tid>>3, r4 = (tid&7)*4;
    ushort4 o;
    o.x = f2b(tile[r4+0][c]); o.y = f2b(tile[r4+1][c]);
    o.z = f2b(tile[r4+2][c]); o.w = f2b(tile[r4+3][c]);
    *(ushort4*)&out[(long)(tc+c)*R + tr+r4] = o;
  }
}

// -- 3-buffer counted-vmcnt bf16 MFMA GEMM, wave-grid WRxWC, per-wave FMxFN ----
template<int WR, int WC, int FM, int FN, int OMODE>
__global__ __launch_bounds__(WR*WC*64, 2) void k_gemm_bt(
  const unsigned short* __restrict__ A, long lda, long sAb,
  const unsigned short* __restrict__ Bt, long ldb, long sBb,
  float* __restrict__ Cf, unsigned short* __restrict__ Cb, long ldc, long sCb,
  const float* __restrict__ bias, int Kiters)
{
  constexpr int WAVES = WR*WC;
  constexpr int BM = WR*FM*16, BN = WC*FN*16;
  constexpr int AR16 = BM/16, TOT16 = (BM+BN)/16;   // 16-row stage units
  constexpr int UNITS = TOT16/WAVES;                // gload_lds per wave per tile
  static_assert(TOT16 % WAVES == 0, "stage units must split across waves");
  __shared__ __align__(16) unsigned short S[3][TOT16*512];
  const int tid = threadIdx.x;
  const int wave = tid>>6, lane = tid&63;
  const int wr = wave/WC, wc = wave%WC;
  const int l15 = lane&15, lhi = lane>>4;
  const int lrow = lane>>2;
  const int lcol = ((lane&3) ^ ((lrow>>1)&3))*8;    // 2-way swizzled source slot

  // XCD-aware bijective swizzle within the z-slice (requires nwg % 8 == 0)
  const int gx = gridDim.x;
  const int nwg = gx*gridDim.y;
  const int id = blockIdx.y*gx + blockIdx.x;
  const int sid = (id&7)*(nwg>>3) + (id>>3);
  const long bm = (long)(sid / gx)*BM, bn = (long)(sid % gx)*BN;

  const unsigned short* Ab  = A  + (long)blockIdx.z*sAb + bm*lda;
  const unsigned short* Btb = Bt + (long)blockIdx.z*sBb + bn*ldb;

  f32x4 acc[FM][FN];
  #pragma unroll
  for (int i=0;i<FM;i++)
    #pragma unroll
    for (int j=0;j<FN;j++) acc[i][j] = (f32x4){0.f,0.f,0.f,0.f};

  auto STAGE = [&](int kt, int buf){
    const long k0 = (long)kt*32;
    #pragma unroll
    for (int u=0; u<UNITS; ++u) {
      const int t = wave + u*WAVES;                  // wave-uniform stage unit
      const unsigned short* g;
      if (t < AR16) g = Ab  + (long)(t*16 + lrow)*lda + k0 + lcol;
      else          g = Btb + (long)((t-AR16)*16 + lrow)*ldb + k0 + lcol;
      gload_lds16(g, &S[buf][t*512]);                // linear dest, swz source
    }
  };
  auto COMPUTE = [&](int buf){
    const unsigned short* Sb = S[buf];
    bf16x8 bfr[FN];
    #pragma unroll
    for (int j=0;j<FN;j++) {
      const int r = wc*(FN*16) + j*16 + l15;
      bfr[j] = *(const bf16x8*)&Sb[BM*32 + r*32 + ((lhi ^ ((r>>1)&3))*8)];
    }
    #pragma unroll
    for (int i=0;i<FM;i++) {
      const int r = wr*(FM*16) + i*16 + l15;
      bf16x8 a = *(const bf16x8*)&Sb[r*32 + ((lhi ^ ((r>>1)&3))*8)];
      #pragma unroll
      for (int j=0;j<FN;j++)
        acc[i][j] = __builtin_amdgcn_mfma_f32_16x16x32_bf16(a, bfr[j], acc[i][j], 0,0,0);
    }
  };

  STAGE(0, 0);
  if (Kiters > 1) STAGE(1, 1);
  for (int kt=0; kt<Kiters; ++kt) {
    if (kt+1 < Kiters) waitcnt_vm<UNITS>();          // tile kt retired; kt+1 in flight
    else               waitcnt_vm<0>();              // last tile: full drain
    __builtin_amdgcn_s_barrier();                    // raw barrier: no auto-drain
    __builtin_amdgcn_sched_barrier(0);
    COMPUTE(kt%3);
    if (kt+2 < Kiters) STAGE(kt+2, (kt+2)%3);        // buf freed by barrier above
  }

  #pragma unroll
  for (int i=0;i<FM;i++) {
    #pragma unroll
    for (int j=0;j<FN;j++) {
      long col = bn + wc*(FN*16) + j*16 + l15;
      float bb = bias ? bias[col] : 0.f;
      #pragma unroll
      for (int q=0;q<4;q++) {
        long row = bm + wr*(FM*16) + i*16 + lhi*4 + q;
        float v = acc[i][j][q] + bb;
        long off = (long)blockIdx.z*sCb + row*ldc + col;
        if constexpr (OMODE==0 || OMODE==2) Cf[off] = v;
        if constexpr (OMODE==1 || OMODE==2) Cb[off] = f2b(v);
      }
    }
  }
}

// ---- combine bf16 split-K partials + f32 bias -> bf16 (row = 1024) ----
__global__ __launch_bounds__(256) void k_combine_bias_bf16(
    const unsigned short* __restrict__ p, long sz, const float* __restrict__ bias,
    unsigned short* __restrict__ outb)
{
  const long t = blockIdx.x;
  const int tid = threadIdx.x;
  ushort4 a = ((const ushort4*)(p + t*1024))[tid];
  ushort4 b = ((const ushort4*)(p + sz + t*1024))[tid];
  float4 bi = ((const float4*)bias)[tid];
  ushort4 o;
  o.x = f2b(b2f(a.x)+b2f(b.x)+bi.x); o.y = f2b(b2f(a.y)+b2f(b.y)+bi.y);
  o.z = f2b(b2f(a.z)+b2f(b.z)+bi.z); o.w = f2b(b2f(a.w)+b2f(b.w)+bi.w);
  ((ushort4*)(outb + t*1024))[tid] = o;
}

// ------------- top-16 + softmax over bf16 scores, packed sortable keys --------
__global__ __launch_bounds__(256) void k_topk_softmax(const unsigned short* __restrict__ scores,
                                                      int* __restrict__ topidx,
                                                      float* __restrict__ topw)
{
  const int tid = threadIdx.x, wave = tid>>6, lane = tid&63;
  const long t = blockIdx.x;
  const unsigned short* row = scores + t*2048;
  const int base = wave*512 + lane*8;
  unsigned k0,k1,k2,k3,k4,k5,k6,k7;
  {
    uint4 v4 = *(const uint4*)(row + base);
    unsigned short u[8] = {
      (unsigned short)(v4.x&0xFFFF),(unsigned short)(v4.x>>16),
      (unsigned short)(v4.y&0xFFFF),(unsigned short)(v4.y>>16),
      (unsigned short)(v4.z&0xFFFF),(unsigned short)(v4.z>>16),
      (unsigned short)(v4.w&0xFFFF),(unsigned short)(v4.w>>16) };
    unsigned kk[8];
    #pragma unroll
    for (int e=0;e<8;e++){
      unsigned m = (u[e]&0x8000u) ? (unsigned)(~u[e] & 0xFFFFu)
                                  : ((unsigned)u[e] | 0x8000u);
      kk[e] = (m<<16) | (unsigned)(2047 - (base+e));
    }
    k0=kk[0];k1=kk[1];k2=kk[2];k3=kk[3];k4=kk[4];k5=kk[5];k6=kk[6];k7=kk[7];
  }
  #define CX(x,y) { unsigned mx = x>y?x:y, mn = x>y?y:x; x=mx; y=mn; }
  CX(k0,k1) CX(k2,k3) CX(k4,k5) CX(k6,k7)
  CX(k0,k2) CX(k1,k3) CX(k4,k6) CX(k5,k7)
  CX(k1,k2) CX(k5,k6)
  CX(k0,k4) CX(k1,k5) CX(k2,k6) CX(k3,k7)
  CX(k2,k4) CX(k3,k5)
  CX(k1,k2) CX(k3,k4) CX(k5,k6)
  #undef CX

  __shared__ unsigned wk[4][16];
  unsigned my1 = 0;
  for (int it=0; it<16; ++it){
    unsigned best = k0;
    #pragma unroll
    for (int off=1; off<64; off<<=1){
      unsigned o = __shfl_xor(best, off);
      best = o>best ? o : best;
    }
    if (lane==it) my1 = best;
    bool own = (k0==best);
    k0 = own?k1:k0; k1 = own?k2:k1; k2 = own?k3:k2; k3 = own?k4:k3;
    k4 = own?k5:k4; k5 = own?k6:k5; k6 = own?k7:k6; k7 = own?0u:k7;
  }
  if (lane < 16) wk[wave][lane] = my1;
  __syncthreads();
  if (wave == 0){
    unsigned c = wk[lane>>4][lane&15];
    unsigned my2 = 0;
    for (int it=0; it<16; ++it){
      unsigned best = c;
      #pragma unroll
      for (int off=1; off<64; off<<=1){
        unsigned o = __shfl_xor(best, off);
        best = o>best ? o : best;
      }
      if (lane==it) my2 = best;
      c = (c==best) ? 0u : c;
    }
    int idx = 2047 - (int)(my2 & 0x7FFu);
    float val = -1e30f;
    if (lane < 16) val = b2f(row[idx]);
    float m0 = __shfl(val, 0);                 // lane 0 = first extracted = max
    float e = (lane < 16) ? __expf(val - m0) : 0.f;
    float s = e;
    #pragma unroll
    for (int off=1; off<64; off<<=1) s += __shfl_xor(s, off);
    if (lane < 16){
      topw[t*16+lane]   = e/s;
      topidx[t*16+lane] = idx;
    }
  }
}

// ---- gather + weighted combine + GELU, XCD-partitioned along d_ff ----
__global__ __launch_bounds__(256) void k_gather_gelu(const int* __restrict__ topidx,
                                                     const float* __restrict__ topw,
                                                     const unsigned short* __restrict__ firing,
                                                     unsigned short* __restrict__ gact)
{
  __shared__ int idx[4][16]; __shared__ float w[4][16];
  const int tid = threadIdx.x;
  const int c = blockIdx.x & 7;
  const long t0 = (long)(blockIdx.x >> 3) * 4;
  if (tid < 64) {
    int tok = tid >> 4, k = tid & 15;
    idx[tok][k] = topidx[(t0+tok)*16 + k];
    w[tok][k]   = topw[(t0+tok)*16 + k];
  }
  __syncthreads();
  const int tok = tid >> 6, lane = tid & 63;
  const int f0 = c*512 + lane*8;
  float acc[8] = {0,0,0,0,0,0,0,0};
  #pragma unroll
  for (int k=0;k<16;k++) {
    uint4 v = *(const uint4*)(firing + (long)idx[tok][k]*4096 + f0);
    const unsigned short* pu = (const unsigned short*)&v;
    float wk = w[tok][k];
    #pragma unroll
    for (int e=0;e<8;e++) acc[e] += wk * b2f(pu[e]);
  }
  float g[8];
  #pragma unroll
  for (int e=0;e<8;e++) g[e] = gelu_exact(acc[e]);
  uint4 ov;
  ov.x = pack2(g[0],g[1]); ov.y = pack2(g[2],g[3]);
  ov.z = pack2(g[4],g[5]); ov.w = pack2(g[6],g[7]);
  *(uint4*)(gact + (t0+tok)*4096 + f0) = ov;
}

// ---------------- V transpose per (b,h): vT[bh][d][t] = qkv[b,t][2048+h*64+d] --
__global__ __launch_bounds__(256) void k_vtrans(const unsigned short* __restrict__ qkv,
                                                unsigned short* __restrict__ vT)
{
  __shared__ unsigned short tile[64][65];
  int bh = blockIdx.y; int b = bh>>4, h = bh&15;
  long t0 = (long)blockIdx.x*64;
  const int tid = threadIdx.x;
  #pragma unroll
  for (int s=0;s<16;s++) {
    int i = tid + s*256;
    int r = i>>6, c = i&63;
    tile[r][c] = qkv[ (long)(b*1024 + t0 + r)*3072 + 2048 + h*64 + c ];
  }
  __syncthreads();
  #pragma unroll
  for (int s=0;s<16;s++) {
    int i = tid + s*256;
    int c = i>>6, r = i&63;
    vT[ (long)bh*65536 + (long)c*1024 + t0 + r ] = tile[r][c];
  }
}

// ---------------- fused flash attention, 8-wave (16 q-rows/wave) ----------------
// K and V both staged in LDS (double-buffered). Round-14 showed K-from-L2
// puts a 16x ~200cy dependent chain on the MFMA critical path (-37us).
__global__ __launch_bounds__(512, 4) void k_flash_attn(
  const unsigned short* __restrict__ qkv,   // [4][1024][3072]
  const unsigned short* __restrict__ vT,    // [64 bh][64 d][1024 t]
  unsigned short* __restrict__ ctx)         // [4][1024][1024]
{
  __shared__ __align__(16) unsigned short Ks[2][128*64];
  __shared__ __align__(16) unsigned short Vs[2][64*128];
  const int tid = threadIdx.x;
  const int wave = tid>>6, lane = tid&63;
  const int l15 = lane&15, lhi = lane>>4;
  const int bh = blockIdx.x, b = bh>>4, h = bh&15;
  const long q0 = (long)blockIdx.y*128;
  const unsigned short* Qg = qkv + ((long)b*1024 + q0)*3072 + h*64;
  const unsigned short* Kg = qkv + (long)b*1024*3072 + 1024 + h*64;
  const unsigned short* Vg = vT + (long)bh*65536;

  auto STAGE_KV = [&](int t, int s){
    const long kv0 = (long)t*128;
    const int sr = lane>>3, sc = (lane&7)^sr;
    #pragma unroll
    for (int uu=0; uu<2; ++uu){
      int u = wave + uu*8;
      gload_lds16(Kg + (kv0 + u*8 + sr)*3072 + sc*8, &Ks[s][u*512]);
    }
    const int vc = (lane&15) ^ ((wave&1)*4 + lhi);   // u&1 == wave&1 (uu*8 even)
    #pragma unroll
    for (int uu=0; uu<2; ++uu){
      int u = wave + uu*8;
      gload_lds16(Vg + (long)(u*4+lhi)*1024 + kv0 + vc*8, &Vs[s][u*512]);
    }
  };

  STAGE_KV(0, 0);

  bf16x8 qf[2];
  {
    const long r = wave*16 + l15;
    qf[0] = *(const bf16x8*)(Qg + r*3072 + lhi*8);
    qf[1] = *(const bf16x8*)(Qg + r*3072 + 32 + lhi*8);
  }
  __syncthreads();   // K/V tile 0 resident

  f32x4 acco[4];
  #pragma unroll
  for (int nf=0;nf<4;nf++) acco[nf] = (f32x4){0.f,0.f,0.f,0.f};
  float m_run = -1e30f, l_run = 0.f;

  int sel = 0;
  for (int t=0; t<8; ++t) {
    if (t < 7) STAGE_KV(t+1, sel^1);
    f32x4 accs[8];
    #pragma unroll
    for (int fk=0;fk<8;fk++){
      accs[fk] = (f32x4){0.f,0.f,0.f,0.f};
      const int r = fk*16 + l15;
      bf16x8 k0 = *(const bf16x8*)&Ks[sel][r*64 + ((lhi^(r&7))*8)];
      accs[fk] = __builtin_amdgcn_mfma_f32_16x16x32_bf16(k0, qf[0], accs[fk],0,0,0);
      bf16x8 k1 = *(const bf16x8*)&Ks[sel][r*64 + (((4+lhi)^(r&7))*8)];
      accs[fk] = __builtin_amdgcn_mfma_f32_16x16x32_bf16(k1, qf[1], accs[fk],0,0,0);
    }
    float mt = -1e30f;
    #pragma unroll
    for (int fk=0;fk<8;fk++)
      #pragma unroll
      for (int q=0;q<4;q++) mt = fmaxf(mt, accs[fk][q]);
    mt = fmaxf(mt, __shfl_xor(mt,16));
    mt = fmaxf(mt, __shfl_xor(mt,32));
    mt *= 0.125f;
    if (!__all(mt <= m_run + 8.f)) {                  // T13 defer-max, THR=8
      float mnew = fmaxf(m_run, mt);
      float fj = __expf(m_run - mnew);
      l_run *= fj;
      #pragma unroll
      for (int q=0;q<4;q++){
        float fr = __shfl(fj, (lane&48)|(lhi*4+q));   // O-row q' = lhi*4+q
        #pragma unroll
        for (int nf=0;nf<4;nf++) acco[nf][q] *= fr;
      }
      m_run = mnew;
    }
    bf16x8 pa[4];
    float ssum = 0.f;
    #pragma unroll
    for (int fk=0;fk<8;fk++)
      #pragma unroll
      for (int q=0;q<4;q++){
        float p = __expf(accs[fk][q]*0.125f - m_run);
        ssum += p;
        pa[fk>>1][(fk&1)*4+q] = (__bf16)p;            // k = (fk>>1)*32+(fk&1)*16+lhi*4+q
      }
    ssum += __shfl_xor(ssum,16);
    ssum += __shfl_xor(ssum,32);
    l_run += ssum;
    #pragma unroll
    for (int kk=0;kk<4;kk++)
      #pragma unroll
      for (int nf=0;nf<4;nf++){
        const int rv = nf*16 + l15;
        const int cb = kk*4 + (lhi>>1);
        bf16x4 v0 = *(const bf16x4*)&Vs[sel][rv*128 + (( cb   ^(l15&7))*8) + (lhi&1)*4];
        bf16x4 v1 = *(const bf16x4*)&Vs[sel][rv*128 + (((cb+2)^(l15&7))*8) + (lhi&1)*4];
        bf16x8 vb = __builtin_shufflevector(v0, v1, 0,1,2,3,4,5,6,7);
        acco[nf] = __builtin_amdgcn_mfma_f32_16x16x32_bf16(pa[kk], vb, acco[nf],0,0,0);
      }
    __syncthreads();    // tile t+1 resident; buffers safe to swap
    sel ^= 1;
  }

  #pragma unroll
  for (int q=0;q<4;q++){
    float lr = __shfl(l_run, (lane&48)|(lhi*4+q));
    float inv = 1.f/lr;
    long row = q0 + wave*16 + lhi*4 + q;
    #pragma unroll
    for (int nf=0;nf<4;nf++)
      ctx[((long)b*1024 + row)*1024 + h*64 + nf*16 + l15] = f2b(acco[nf][q]*inv);
  }
}

// ------- fused double residual+LN: out = LN2( LN1(x + attnb) + neub ) ---------
__global__ __launch_bounds__(256) void k_ln2(const float* __restrict__ x,
                                             const unsigned short* __restrict__ attnb,
                                             const unsigned short* __restrict__ neub,
                                             const float* __restrict__ g1,
                                             const float* __restrict__ be1,
                                             const float* __restrict__ g2,
                                             const float* __restrict__ be2,
                                             float* __restrict__ out)
{
  const long t = blockIdx.x;
  const int tid = threadIdx.x;
  const int wave = tid>>6, lane = tid&63;
  __shared__ float s1[4], s2[4], s3[4], s4[4];
  float4 xv = ((const float4*)(x + t*1024))[tid];
  ushort4 ua = ((const ushort4*)(attnb + t*1024))[tid];
  float4 sv = { xv.x + b2f(ua.x), xv.y + b2f(ua.y),
                xv.z + b2f(ua.z), xv.w + b2f(ua.w) };
  float sum = sv.x+sv.y+sv.z+sv.w;
  float sq  = sv.x*sv.x + sv.y*sv.y + sv.z*sv.z + sv.w*sv.w;
  #pragma unroll
  for (int off=32; off; off>>=1){ sum += __shfl_xor(sum,off); sq += __shfl_xor(sq,off); }
  if (lane==0){ s1[wave]=sum; s2[wave]=sq; }
  __syncthreads();
  sum = s1[0]+s1[1]+s1[2]+s1[3];
  sq  = s2[0]+s2[1]+s2[2]+s2[3];
  float mu  = sum * (1.f/1024.f);
  float var = sq * (1.f/1024.f) - mu*mu;
  float rs  = rsqrtf(var + 1e-5f);
  float4 g1v  = ((const float4*)g1)[tid];
  float4 be1v = ((const float4*)be1)[tid];
  ushort4 un = ((const ushort4*)(neub + t*1024))[tid];
  float4 hv = { (sv.x-mu)*rs*g1v.x + be1v.x + b2f(un.x),
                (sv.y-mu)*rs*g1v.y + be1v.y + b2f(un.y),
                (sv.z-mu)*rs*g1v.z + be1v.z + b2f(un.z),
                (sv.w-mu)*rs*g1v.w + be1v.w + b2f(un.w) };
  float sum2 = hv.x+hv.y+hv.z+hv.w;
  float sq2  = hv.x*hv.x + hv.y*hv.y + hv.z*hv.z + hv.w*hv.w;
  #pragma unroll
  for (int off=32; off; off>>=1){ sum2 += __shfl_xor(sum2,off); sq2 += __shfl_xor(sq2,off); }
  if (lane==0){ s3[wave]=sum2; s4[wave]=sq2; }
  __syncthreads();
  sum2 = s3[0]+s3[1]+s3[2]+s3[3];
  sq2  = s4[0]+s4[1]+s4[2]+s4[3];
  float mu2  = sum2 * (1.f/1024.f);
  float var2 = sq2 * (1.f/1024.f) - mu2*mu2;
  float rs2  = rsqrtf(var2 + 1e-5f);
  float4 g2v  = ((const float4*)g2)[tid];
  float4 be2v = ((const float4*)be2)[tid];
  float4 ov = { (hv.x-mu2)*rs2*g2v.x + be2v.x,
                (hv.y-mu2)*rs2*g2v.y + be2v.y,
                (hv.z-mu2)*rs2*g2v.z + be2v.z,
                (hv.w-mu2)*rs2*g2v.w + be2v.w };
  ((float4*)(out + t*1024))[tid] = ov;
}

// =====================================================================
extern "C" void kernel_launch(void* const* d_in, const int* in_sizes, int n_in,
                              void* d_out, int out_size, void* d_ws, size_t ws_size,
                              hipStream_t stream)
{
  const float* x        = (const float*)d_in[0];
  const float* w_router = (const float*)d_in[1];
  const float* b_router = (const float*)d_in[2];
  const float* firing   = (const float*)d_in[3];
  const float* w_pool   = (const float*)d_in[4];
  const float* b_pool   = (const float*)d_in[5];
  const float* w_in     = (const float*)d_in[6];
  const float* b_in     = (const float*)d_in[7];
  const float* w_ao     = (const float*)d_in[8];
  const float* b_ao     = (const float*)d_in[9];
  const float* g1       = (const float*)d_in[10];
  const float* be1      = (const float*)d_in[11];
  const float* g2       = (const float*)d_in[12];
  const float* be2      = (const float*)d_in[13];
  float* out = (float*)d_out;
  char* ws = (char*)d_ws;

  // ws layout (bytes); P region aliased: scoresb(bf16,16MB) -> gact(bf16,32MB).
  // poolpb (16MB bf16 split-K partials) aliases vT+ctx (written later).
  unsigned short* xb    = (unsigned short*)(ws + 0);          //  8,388,608
  unsigned short* wrT   = (unsigned short*)(ws + 8388608);    //  4,194,304
  unsigned short* firb  = (unsigned short*)(ws + 12582912);   // 16,777,216
  unsigned short* wpoT  = (unsigned short*)(ws + 29360128);   //  8,388,608
  unsigned short* winT  = (unsigned short*)(ws + 37748736);   //  6,291,456
  unsigned short* waoT  = (unsigned short*)(ws + 44040192);   //  2,097,152
  unsigned short* scoresb = (unsigned short*)(ws + 46137344); // 16,777,216 (P)
  unsigned short* gact  = (unsigned short*)(ws + 46137344);   // alias P (32MB)
  int*    topi          = (int*)(ws + 79691776);              //    262,144
  float*  topw          = (float*)(ws + 79953920);            //    262,144
  unsigned short* attnb = (unsigned short*)(ws + 80216064);   //  8,388,608
  unsigned short* neub  = (unsigned short*)(ws + 96993280);   //  8,388,608
  unsigned short* qkvb  = (unsigned short*)(ws + 105381888);  // 25,165,824
  unsigned short* vT    = (unsigned short*)(ws + 130547712);  //  8,388,608
  unsigned short* ctx   = (unsigned short*)(ws + 138936320);  //  8,388,608
  unsigned short* poolpb= (unsigned short*)(ws + 130547712);  // 16,777,216 alias

  if (ws_size < 164102144u) return; // insufficient scratch: fail loudly

  // ---- prep: all casts + weight transposes in one dispatch ----
  k_prep<<<22528, 256, 0, stream>>>(x, xb, firing, firb, w_router, wrT,
                                    w_pool, wpoT, w_in, winT, w_ao, waoT);

  // ---- router: scores = x @ w_router + b_router -> bf16 (128x128, 512 wg) ----
  k_gemm_bt<2,2,4,4,1><<<dim3(16,32,1),256,0,stream>>>(xb,1024,0, wrT,1024,0,
        nullptr,scoresb,2048,0, b_router, 32);
  k_topk_softmax<<<4096,256,0,stream>>>(scoresb, topi, topw);
  k_gather_gelu<<<8192,256,0,stream>>>(topi, topw, firb, gact);

  // ---- pool: split-K=2, 128x128 tiles, bf16 partials; combine adds bias ----
  k_gemm_bt<2,2,4,4,1><<<dim3(8,32,2),256,0,stream>>>(gact,4096,2048, wpoT,4096,2048,
        nullptr,poolpb,1024,4194304, nullptr, 64);
  k_combine_bias_bf16<<<4096,256,0,stream>>>(poolpb, 4194304, b_pool, neub);

  // ---- qkv = neuron_out @ w_in + b_in (bf16; 128x128, 768 wg) ----
  k_gemm_bt<2,2,4,4,1><<<dim3(24,32,1),256,0,stream>>>(neub,1024,0, winT,1024,0,
        nullptr,qkvb,3072,0, b_in, 32);

  // ---- attention: V transpose + fused flash (XCD-local K/V, 8-wave blocks) ----
  k_vtrans<<<dim3(16,64),256,0,stream>>>(qkvb, vT);
  k_flash_attn<<<dim3(64,8),512,0,stream>>>(qkvb, vT, ctx);

  // ---- attn_out = ctx @ w_attn_out + b_ao (128x64, 512 wg, bf16 out) ----
  k_gemm_bt<2,2,4,2,1><<<dim3(16,32,1),256,0,stream>>>(ctx,1024,0, waoT,1024,0,
        nullptr,attnb,1024,0, b_ao, 32);

  // ---- out = LN2( LN1(x + attn_out) + neuron_out )  (fused, no hbuf) ----
  k_ln2<<<4096,256,0,stream>>>(x, attnb, neub, g1, be1, g2, be2, out);
}